// Round 16
// baseline (908.259 us; speedup 1.0000x reference)
//
#include <hip/hip_runtime.h>

#define LRC 0.01f
#define LSEQ 4096
#define HIDDIM 128

typedef float f32x2 __attribute__((ext_vector_type(2)));
typedef unsigned int u32x2 __attribute__((ext_vector_type(2)));

#define RL(x, L) __int_as_float(__builtin_amdgcn_readlane(__float_as_int(x), (L)))
#define RORADD(x, ctrl)                                                      \
  x += __int_as_float(__builtin_amdgcn_update_dpp(                           \
      0, __float_as_int(x), (ctrl), 0xf, 0xf, true))

// (validated R5..R14) 4 concurrent 64-lane sums, row-mapped outputs:
// row g holds sum of x_{sig(g)}, sig=[0,2,1,3]; rowlead write at
// sm[base+sig] lands value c at sm[base+c].
__device__ __forceinline__ float allred4(float x0, float x1, float x2,
                                         float x3) {
  u32x2 s1 = __builtin_amdgcn_permlane32_swap(__float_as_uint(x0),
                                              __float_as_uint(x1), false, false);
  float z01 = __uint_as_float(s1.x) + __uint_as_float(s1.y);
  u32x2 s2 = __builtin_amdgcn_permlane32_swap(__float_as_uint(x2),
                                              __float_as_uint(x3), false, false);
  float z23 = __uint_as_float(s2.x) + __uint_as_float(s2.y);
  u32x2 s3 = __builtin_amdgcn_permlane16_swap(__float_as_uint(z01),
                                              __float_as_uint(z23), false, false);
  float y = __uint_as_float(s3.x) + __uint_as_float(s3.y);
  RORADD(y, 0x128); RORADD(y, 0x124); RORADD(y, 0x122); RORADD(y, 0x121);
  return y;
}

// (validated R6/R13) 64-lane sum, all-lane-uniform result.
__device__ __forceinline__ float allred1(float x) {
  u32x2 s1 = __builtin_amdgcn_permlane32_swap(__float_as_uint(x),
                                              __float_as_uint(x), false, false);
  float z = __uint_as_float(s1.x) + __uint_as_float(s1.y);
  u32x2 s2 = __builtin_amdgcn_permlane16_swap(__float_as_uint(z),
                                              __float_as_uint(z), false, false);
  z = __uint_as_float(s2.x) + __uint_as_float(s2.y);
  RORADD(z, 0x128); RORADD(z, 0x124); RORADD(z, 0x122); RORADD(z, 0x121);
  return z;
}

// Barrier WITHOUT vmcnt drain: global prefetches stay in flight.
#define BAR() asm volatile("s_waitcnt lgkmcnt(0)\n\ts_barrier" ::: "memory")

__device__ __forceinline__ float dot2(f32x2 a, f32x2 b) {
  return fmaf(a.x, b.x, a.y * b.y);
}

struct PendT {
  float glx, gly, r0, r1, r2, r3, r4, r5, r6, r7;
};

// R13 (E=2, 533us) duplicated: TWO chains (batches 2b, 2b+1) per wave pair.
// LDS per chain (80 floats): TP[ep][2][8] at ep*16 | KK[ep][5] at 32+ep*5 |
// DA[ep][2][8] at 48+ep*16. Chain Q at +80. One barrier per epoch (2 steps).
__global__ __launch_bounds__(128) void ttt_kernel(
    const float* __restrict__ h, const float* __restrict__ W1,
    const float* __restrict__ b1, const float* __restrict__ W2,
    const float* __restrict__ b2, float* __restrict__ out) {
  __shared__ __align__(16) float sm[160];
  const int bp = blockIdx.x * 2;
  const int tid = threadIdx.x;
  const int wv = tid >> 6;
  const int lane = tid & 63;
  const int g = lane >> 4;
  const int sig = ((g & 1) << 1) | (g >> 1);
  const int d0 = lane * 2;
  const bool rowlead = ((lane & 15) == 0);
  const float* __restrict__ hbP = h + (size_t)bp * (LSEQ * HIDDIM);
  const float* __restrict__ hbQ = hbP + (size_t)LSEQ * HIDDIM;

  if (wv == 0) {
    // =============== WAVE A: two serial cores (chains P, Q) ===============
    const float cneg = -(LRC * 2.0f / (float)HIDDIM);
    f32x2 w2P[8], w2Q[8];
#pragma unroll
    for (int i = 0; i < 8; ++i) {
      f32x2 t;
      t.x = W2[(size_t)d0 * 8 + i];
      t.y = W2[(size_t)(d0 + 1) * 8 + i];
      w2P[i] = t;
      w2Q[i] = t;
    }
    f32x2 b2c = *(const f32x2*)(b2 + d0);
    f32x2 b2P = b2c, b2Q = b2c;
    float b1AP = b1[sig], b1BP = b1[4 + sig];
    float b1AQ = b1AP, b1BQ = b1BP;
    f32x2 vP[4], vQ[4];
#pragma unroll
    for (int x = 0; x < 4; ++x) {
      vP[x] = *(const f32x2*)(hbP + (size_t)(2 * x + 1) * HIDDIM + d0);
      vQ[x] = *(const f32x2*)(hbQ + (size_t)(2 * x + 1) * HIDDIM + d0);
    }
    PendT pdP = {}, pdQ = {};
    float dm2AP = 0, dm2BP = 0, dm1AP = 0, dm1BP = 0;
    float dm2AQ = 0, dm2BQ = 0, dm1AQ = 0, dm1BQ = 0;

    auto CORE = [&](f32x2(&w2v)[8], f32x2& b2v, float aA, float aB, f32x2 vcur,
                    float& daAo, float& daBo, PendT& pd, bool defer) {
      float rA = fmaxf(aA, 0.0f), rB = fmaxf(aB, 0.0f);
      float r0 = RL(rA, 0), r1 = RL(rA, 32), r2 = RL(rA, 16), r3 = RL(rA, 48);
      float r4 = RL(rB, 0), r5 = RL(rB, 32), r6 = RL(rB, 16), r7 = RL(rB, 48);
      float px0 = fmaf(w2v[0].x, r0, b2v.x), py0 = fmaf(w2v[0].y, r0, b2v.y);
      float px1 = w2v[1].x * r1, py1 = w2v[1].y * r1;
      px0 = fmaf(w2v[2].x, r2, px0); py0 = fmaf(w2v[2].y, r2, py0);
      px1 = fmaf(w2v[3].x, r3, px1); py1 = fmaf(w2v[3].y, r3, py1);
      px0 = fmaf(w2v[4].x, r4, px0); py0 = fmaf(w2v[4].y, r4, py0);
      px1 = fmaf(w2v[5].x, r5, px1); py1 = fmaf(w2v[5].y, r5, py1);
      px0 = fmaf(w2v[6].x, r6, px0); py0 = fmaf(w2v[6].y, r6, py0);
      px1 = fmaf(w2v[7].x, r7, px1); py1 = fmaf(w2v[7].y, r7, py1);
      float glx = (px0 + px1 - vcur.x) * cneg;
      float gly = (py0 + py1 - vcur.y) * cneg;
      float dp[8];
#pragma unroll
      for (int i = 0; i < 8; ++i) dp[i] = fmaf(w2v[i].x, glx, w2v[i].y * gly);
      float zA = allred4(dp[0], dp[1], dp[2], dp[3]);
      float zB = allred4(dp[4], dp[5], dp[6], dp[7]);
      daAo = (aA > 0.0f) ? zA : 0.0f;  // == -lr * da_ref
      daBo = (aB > 0.0f) ? zB : 0.0f;
      if (!defer) {
        w2v[0].x = fmaf(glx, r0, w2v[0].x); w2v[0].y = fmaf(gly, r0, w2v[0].y);
        w2v[1].x = fmaf(glx, r1, w2v[1].x); w2v[1].y = fmaf(gly, r1, w2v[1].y);
        w2v[2].x = fmaf(glx, r2, w2v[2].x); w2v[2].y = fmaf(gly, r2, w2v[2].y);
        w2v[3].x = fmaf(glx, r3, w2v[3].x); w2v[3].y = fmaf(gly, r3, w2v[3].y);
        w2v[4].x = fmaf(glx, r4, w2v[4].x); w2v[4].y = fmaf(gly, r4, w2v[4].y);
        w2v[5].x = fmaf(glx, r5, w2v[5].x); w2v[5].y = fmaf(gly, r5, w2v[5].y);
        w2v[6].x = fmaf(glx, r6, w2v[6].x); w2v[6].y = fmaf(gly, r6, w2v[6].y);
        w2v[7].x = fmaf(glx, r7, w2v[7].x); w2v[7].y = fmaf(gly, r7, w2v[7].y);
        b2v.x += glx;
        b2v.y += gly;
      } else {
        pd.glx = glx; pd.gly = gly;
        pd.r0 = r0; pd.r1 = r1; pd.r2 = r2; pd.r3 = r3;
        pd.r4 = r4; pd.r5 = r5; pd.r6 = r6; pd.r7 = r7;
      }
    };
    auto PEND = [&](f32x2(&w2v)[8], f32x2& b2v, PendT& pd) {
      w2v[0].x = fmaf(pd.glx, pd.r0, w2v[0].x);
      w2v[0].y = fmaf(pd.gly, pd.r0, w2v[0].y);
      w2v[1].x = fmaf(pd.glx, pd.r1, w2v[1].x);
      w2v[1].y = fmaf(pd.gly, pd.r1, w2v[1].y);
      w2v[2].x = fmaf(pd.glx, pd.r2, w2v[2].x);
      w2v[2].y = fmaf(pd.gly, pd.r2, w2v[2].y);
      w2v[3].x = fmaf(pd.glx, pd.r3, w2v[3].x);
      w2v[3].y = fmaf(pd.gly, pd.r3, w2v[3].y);
      w2v[4].x = fmaf(pd.glx, pd.r4, w2v[4].x);
      w2v[4].y = fmaf(pd.gly, pd.r4, w2v[4].y);
      w2v[5].x = fmaf(pd.glx, pd.r5, w2v[5].x);
      w2v[5].y = fmaf(pd.gly, pd.r5, w2v[5].y);
      w2v[6].x = fmaf(pd.glx, pd.r6, w2v[6].x);
      w2v[6].y = fmaf(pd.gly, pd.r6, w2v[6].y);
      w2v[7].x = fmaf(pd.glx, pd.r7, w2v[7].x);
      w2v[7].y = fmaf(pd.gly, pd.r7, w2v[7].y);
      b2v.x += pd.glx;
      b2v.y += pd.gly;
    };

    BAR();  // init: B wrote buffer 0 (both chains)

    auto EPA = [&](int ep, int e) {
      const int tpo = ep * 16, kko = 32 + ep * 5, dao = 48 + ep * 16;
      float t0AP = sm[tpo + sig], t0BP = sm[tpo + 4 + sig];
      float t1AP = sm[tpo + 8 + sig], t1BP = sm[tpo + 12 + sig];
      float k1P = sm[kko], k2P = sm[kko + 1], k3P = sm[kko + 2],
            k4P = sm[kko + 3], k5P = sm[kko + 4];
      float t0AQ = sm[80 + tpo + sig], t0BQ = sm[80 + tpo + 4 + sig];
      float t1AQ = sm[80 + tpo + 8 + sig], t1BQ = sm[80 + tpo + 12 + sig];
      float k1Q = sm[80 + kko], k2Q = sm[80 + kko + 1], k3Q = sm[80 + kko + 2],
            k4Q = sm[80 + kko + 3], k5Q = sm[80 + kko + 4];
      int rv0 = 4 * e + 9;  if (rv0 > 4095) rv0 = 4095;
      int rv1 = 4 * e + 11; if (rv1 > 4095) rv1 = 4095;
      f32x2 iP0 = *(const f32x2*)(hbP + (size_t)rv0 * HIDDIM + d0);
      f32x2 iP1 = *(const f32x2*)(hbP + (size_t)rv1 * HIDDIM + d0);
      f32x2 iQ0 = *(const f32x2*)(hbQ + (size_t)rv0 * HIDDIM + d0);
      f32x2 iQ1 = *(const f32x2*)(hbQ + (size_t)rv1 * HIDDIM + d0);
      PEND(w2P, b2P, pdP);  // prev epoch's deferred updates; shadow LDS reads
      PEND(w2Q, b2Q, pdQ);
      // step P = 2e, both chains
      float aAP = fmaf(dm2AP, k1P, fmaf(dm1AP, k2P, t0AP + b1AP));
      float aBP = fmaf(dm2BP, k1P, fmaf(dm1BP, k2P, t0BP + b1BP));
      float aAQ = fmaf(dm2AQ, k1Q, fmaf(dm1AQ, k2Q, t0AQ + b1AQ));
      float aBQ = fmaf(dm2BQ, k1Q, fmaf(dm1BQ, k2Q, t0BQ + b1BQ));
      float dPAP, dPBP, dPAQ, dPBQ;
      CORE(w2P, b2P, aAP, aBP, vP[0], dPAP, dPBP, pdP, false);
      CORE(w2Q, b2Q, aAQ, aBQ, vQ[0], dPAQ, dPBQ, pdQ, false);
      if (rowlead) {
        sm[dao + sig] = dPAP;      sm[dao + 4 + sig] = dPBP;
        sm[80 + dao + sig] = dPAQ; sm[80 + dao + 4 + sig] = dPBQ;
      }
      b1AP += dPAP; b1BP += dPBP; b1AQ += dPAQ; b1BQ += dPBQ;
      // step Q = 2e+1, both chains (defer W2/b2 across the barrier)
      float a2AP = fmaf(dm2AP, k3P, fmaf(dm1AP, k4P,
                   fmaf(dPAP, k5P, t1AP + b1AP)));
      float a2BP = fmaf(dm2BP, k3P, fmaf(dm1BP, k4P,
                   fmaf(dPBP, k5P, t1BP + b1BP)));
      float a2AQ = fmaf(dm2AQ, k3Q, fmaf(dm1AQ, k4Q,
                   fmaf(dPAQ, k5Q, t1AQ + b1AQ)));
      float a2BQ = fmaf(dm2BQ, k3Q, fmaf(dm1BQ, k4Q,
                   fmaf(dPBQ, k5Q, t1BQ + b1BQ)));
      float dQAP, dQBP, dQAQ, dQBQ;
      CORE(w2P, b2P, a2AP, a2BP, vP[1], dQAP, dQBP, pdP, true);
      CORE(w2Q, b2Q, a2AQ, a2BQ, vQ[1], dQAQ, dQBQ, pdQ, true);
      if (rowlead) {
        sm[dao + 8 + sig] = dQAP;      sm[dao + 12 + sig] = dQBP;
        sm[80 + dao + 8 + sig] = dQAQ; sm[80 + dao + 12 + sig] = dQBQ;
      }
      b1AP += dQAP; b1BP += dQBP; b1AQ += dQAQ; b1BQ += dQBQ;
      dm2AP = dPAP; dm2BP = dPBP; dm1AP = dQAP; dm1BP = dQBP;
      dm2AQ = dPAQ; dm2BQ = dPBQ; dm1AQ = dQAQ; dm1BQ = dQBQ;
      vP[0] = vP[2]; vP[1] = vP[3]; vP[2] = iP0; vP[3] = iP1;
      vQ[0] = vQ[2]; vQ[1] = vQ[3]; vQ[2] = iQ0; vQ[3] = iQ1;
      BAR();
    };

    for (int pr = 0; pr < 511; ++pr) {
      EPA(0, 2 * pr);
      EPA(1, 2 * pr + 1);
    }
    EPA(0, 1022);
    // ---- tail (buffer ep=1): step 2046 + final predict, both chains ----
    {
      float t0AP = sm[16 + sig], t0BP = sm[20 + sig];
      float t1AP = sm[24 + sig], t1BP = sm[28 + sig];
      float k1P = sm[37], k2P = sm[38], k3P = sm[39], k4P = sm[40],
            k5P = sm[41];
      float t0AQ = sm[96 + sig], t0BQ = sm[100 + sig];
      float t1AQ = sm[104 + sig], t1BQ = sm[108 + sig];
      float k1Q = sm[117], k2Q = sm[118], k3Q = sm[119], k4Q = sm[120],
            k5Q = sm[121];
      PEND(w2P, b2P, pdP);
      PEND(w2Q, b2Q, pdQ);
      float aAP = fmaf(dm2AP, k1P, fmaf(dm1AP, k2P, t0AP + b1AP));
      float aBP = fmaf(dm2BP, k1P, fmaf(dm1BP, k2P, t0BP + b1BP));
      float aAQ = fmaf(dm2AQ, k1Q, fmaf(dm1AQ, k2Q, t0AQ + b1AQ));
      float aBQ = fmaf(dm2BQ, k1Q, fmaf(dm1BQ, k2Q, t0BQ + b1BQ));
      float dAP, dBP, dAQ, dBQ;
      CORE(w2P, b2P, aAP, aBP, vP[0], dAP, dBP, pdP, false);  // step 2046
      CORE(w2Q, b2Q, aAQ, aBQ, vQ[0], dAQ, dBQ, pdQ, false);
      b1AP += dAP; b1BP += dBP; b1AQ += dAQ; b1BQ += dBQ;
      // a(2047) = W1_fin·x + b1_fin  (x fed through as k(2047))
      float fAP = fmaf(dm2AP, k3P, fmaf(dm1AP, k4P,
                  fmaf(dAP, k5P, t1AP + b1AP)));
      float fBP = fmaf(dm2BP, k3P, fmaf(dm1BP, k4P,
                  fmaf(dBP, k5P, t1BP + b1BP)));
      float fAQ = fmaf(dm2AQ, k3Q, fmaf(dm1AQ, k4Q,
                  fmaf(dAQ, k5Q, t1AQ + b1AQ)));
      float fBQ = fmaf(dm2BQ, k3Q, fmaf(dm1BQ, k4Q,
                  fmaf(dBQ, k5Q, t1BQ + b1BQ)));
      {
        float rA = fmaxf(fAP, 0.0f), rB = fmaxf(fBP, 0.0f);
        float r0 = RL(rA, 0), r1 = RL(rA, 32), r2 = RL(rA, 16), r3 = RL(rA, 48);
        float r4 = RL(rB, 0), r5 = RL(rB, 32), r6 = RL(rB, 16), r7 = RL(rB, 48);
        float ox = fmaf(w2P[0].x, r0, b2P.x), oy = fmaf(w2P[0].y, r0, b2P.y);
        ox = fmaf(w2P[1].x, r1, ox); oy = fmaf(w2P[1].y, r1, oy);
        ox = fmaf(w2P[2].x, r2, ox); oy = fmaf(w2P[2].y, r2, oy);
        ox = fmaf(w2P[3].x, r3, ox); oy = fmaf(w2P[3].y, r3, oy);
        ox = fmaf(w2P[4].x, r4, ox); oy = fmaf(w2P[4].y, r4, oy);
        ox = fmaf(w2P[5].x, r5, ox); oy = fmaf(w2P[5].y, r5, oy);
        ox = fmaf(w2P[6].x, r6, ox); oy = fmaf(w2P[6].y, r6, oy);
        ox = fmaf(w2P[7].x, r7, ox); oy = fmaf(w2P[7].y, r7, oy);
        f32x2 o = {ox, oy};
        *(f32x2*)(out + (size_t)bp * HIDDIM + d0) = o;
      }
      {
        float rA = fmaxf(fAQ, 0.0f), rB = fmaxf(fBQ, 0.0f);
        float r0 = RL(rA, 0), r1 = RL(rA, 32), r2 = RL(rA, 16), r3 = RL(rA, 48);
        float r4 = RL(rB, 0), r5 = RL(rB, 32), r6 = RL(rB, 16), r7 = RL(rB, 48);
        float ox = fmaf(w2Q[0].x, r0, b2Q.x), oy = fmaf(w2Q[0].y, r0, b2Q.y);
        ox = fmaf(w2Q[1].x, r1, ox); oy = fmaf(w2Q[1].y, r1, oy);
        ox = fmaf(w2Q[2].x, r2, ox); oy = fmaf(w2Q[2].y, r2, oy);
        ox = fmaf(w2Q[3].x, r3, ox); oy = fmaf(w2Q[3].y, r3, oy);
        ox = fmaf(w2Q[4].x, r4, ox); oy = fmaf(w2Q[4].y, r4, oy);
        ox = fmaf(w2Q[5].x, r5, ox); oy = fmaf(w2Q[5].y, r5, oy);
        ox = fmaf(w2Q[6].x, r6, ox); oy = fmaf(w2Q[6].y, r6, oy);
        ox = fmaf(w2Q[7].x, r7, ox); oy = fmaf(w2Q[7].y, r7, oy);
        f32x2 o = {ox, oy};
        *(f32x2*)(out + (size_t)(bp + 1) * HIDDIM + d0) = o;
      }
    }
  } else {
    // =============== WAVE B: two W1 owners (chains P, Q) ===============
    f32x2 w1P[8], w1Q[8];
#pragma unroll
    for (int i = 0; i < 8; ++i) {
      f32x2 t = *(const f32x2*)(W1 + i * HIDDIM + d0);
      w1P[i] = t;
      w1Q[i] = t;
    }
    f32x2 kRP[6], kRQ[6], kIP0, kIP1, kIQ0, kIQ1;
    kRP[2] = *(const f32x2*)(hbP + 0 * HIDDIM + d0);
    kRP[3] = *(const f32x2*)(hbP + 2 * HIDDIM + d0);
    kRP[4] = *(const f32x2*)(hbP + 4 * HIDDIM + d0);
    kRP[5] = *(const f32x2*)(hbP + 6 * HIDDIM + d0);
    kIP0 = *(const f32x2*)(hbP + 8 * HIDDIM + d0);
    kIP1 = *(const f32x2*)(hbP + 10 * HIDDIM + d0);
    kRP[0] = kRP[2]; kRP[1] = kRP[2];  // dummies (da = 0 at epoch 0)
    kRQ[2] = *(const f32x2*)(hbQ + 0 * HIDDIM + d0);
    kRQ[3] = *(const f32x2*)(hbQ + 2 * HIDDIM + d0);
    kRQ[4] = *(const f32x2*)(hbQ + 4 * HIDDIM + d0);
    kRQ[5] = *(const f32x2*)(hbQ + 6 * HIDDIM + d0);
    kIQ0 = *(const f32x2*)(hbQ + 8 * HIDDIM + d0);
    kIQ1 = *(const f32x2*)(hbQ + 10 * HIDDIM + d0);
    kRQ[0] = kRQ[2]; kRQ[1] = kRQ[2];
    // zero DA[1] both chains (read before A writes anything)
    if (lane < 16) {
      sm[64 + lane] = 0.0f;
      sm[144 + lane] = 0.0f;
    }
    // init buffer 0 both chains: a(0) base, TP(1), kk
    {
      float pa[8], pb[8];
#pragma unroll
      for (int i = 0; i < 8; ++i) {
        pa[i] = dot2(w1P[i], kRP[2]);
        pb[i] = dot2(w1P[i], kRP[3]);
      }
      float zA = allred4(pa[0], pa[1], pa[2], pa[3]);
      float zB = allred4(pa[4], pa[5], pa[6], pa[7]);
      float tA = allred4(pb[0], pb[1], pb[2], pb[3]);
      float tB = allred4(pb[4], pb[5], pb[6], pb[7]);
      float kk01P = allred1(dot2(kRP[2], kRP[3]));
#pragma unroll
      for (int i = 0; i < 8; ++i) {
        pa[i] = dot2(w1Q[i], kRQ[2]);
        pb[i] = dot2(w1Q[i], kRQ[3]);
      }
      float zAq = allred4(pa[0], pa[1], pa[2], pa[3]);
      float zBq = allred4(pa[4], pa[5], pa[6], pa[7]);
      float tAq = allred4(pb[0], pb[1], pb[2], pb[3]);
      float tBq = allred4(pb[4], pb[5], pb[6], pb[7]);
      float kk01Q = allred1(dot2(kRQ[2], kRQ[3]));
      if (rowlead) {
        sm[0 + sig] = zA;       sm[4 + sig] = zB;
        sm[8 + sig] = tA;       sm[12 + sig] = tB;
        sm[80 + 0 + sig] = zAq; sm[80 + 4 + sig] = zBq;
        sm[80 + 8 + sig] = tAq; sm[80 + 12 + sig] = tBq;
      }
      if (lane < 4) {
        sm[32 + lane] = 0.0f;
        sm[112 + lane] = 0.0f;
      }
      if (lane == 0) {
        sm[36] = kk01P;
        sm[116] = kk01Q;
      }
    }
    BAR();  // init

    auto EPB = [&](int ep, int e) {
      const int dao = 48 + (1 - ep) * 16;
      const int tpo = (1 - ep) * 16, kko = 32 + (1 - ep) * 5;
      int m6 = 2 * e + 6, m7 = 2 * e + 7;
      int r6 = (m6 >= 2047) ? 4095 : 2 * m6;
      int r7 = (m7 >= 2047) ? 4095 : 2 * m7;
      f32x2 nP0 = *(const f32x2*)(hbP + (size_t)r6 * HIDDIM + d0);
      f32x2 nP1 = *(const f32x2*)(hbP + (size_t)r7 * HIDDIM + d0);
      f32x2 nQ0 = *(const f32x2*)(hbQ + (size_t)r6 * HIDDIM + d0);
      f32x2 nQ1 = *(const f32x2*)(hbQ + (size_t)r7 * HIDDIM + d0);
      float4 p0 = *(float4*)&sm[dao], p1 = *(float4*)&sm[dao + 4];
      float4 p2 = *(float4*)&sm[dao + 8], p3 = *(float4*)&sm[dao + 12];
      float4 q0 = *(float4*)&sm[80 + dao], q1 = *(float4*)&sm[80 + dao + 4];
      float4 q2 = *(float4*)&sm[80 + dao + 8], q3 = *(float4*)&sm[80 + dao + 12];
      // kk partials (k-only) fill the DA-read shadow
      float c1P = dot2(kRP[2], kRP[4]), c2P = dot2(kRP[3], kRP[4]);
      float c3P = dot2(kRP[2], kRP[5]), c4P = dot2(kRP[3], kRP[5]);
      float c5P = dot2(kRP[4], kRP[5]);
      float c1Q = dot2(kRQ[2], kRQ[4]), c2Q = dot2(kRQ[3], kRQ[4]);
      float c3Q = dot2(kRQ[2], kRQ[5]), c4Q = dot2(kRQ[3], kRQ[5]);
      float c5Q = dot2(kRQ[4], kRQ[5]);
      float ykP = allred4(c1P, c2P, c3P, c4P);
      float y5P = allred1(c5P);
      float ykQ = allred4(c1Q, c2Q, c3Q, c4Q);
      float y5Q = allred1(c5Q);
      if (rowlead) {
        sm[kko + sig] = ykP;
        sm[80 + kko + sig] = ykQ;
      }
      if (lane == 0) {
        sm[kko + 4] = y5P;
        sm[80 + kko + 4] = y5Q;
      }
      float dPa[8] = {p0.x, p0.y, p0.z, p0.w, p1.x, p1.y, p1.z, p1.w};
      float dPb[8] = {p2.x, p2.y, p2.z, p2.w, p3.x, p3.y, p3.z, p3.w};
      float dQa[8] = {q0.x, q0.y, q0.z, q0.w, q1.x, q1.y, q1.z, q1.w};
      float dQb[8] = {q2.x, q2.y, q2.z, q2.w, q3.x, q3.y, q3.z, q3.w};
#pragma unroll
      for (int i = 0; i < 8; ++i) {
        w1P[i].x = fmaf(dPa[i], kRP[0].x, w1P[i].x);
        w1P[i].y = fmaf(dPa[i], kRP[0].y, w1P[i].y);
        w1P[i].x = fmaf(dPb[i], kRP[1].x, w1P[i].x);
        w1P[i].y = fmaf(dPb[i], kRP[1].y, w1P[i].y);
        w1Q[i].x = fmaf(dQa[i], kRQ[0].x, w1Q[i].x);
        w1Q[i].y = fmaf(dQa[i], kRQ[0].y, w1Q[i].y);
        w1Q[i].x = fmaf(dQb[i], kRQ[1].x, w1Q[i].x);
        w1Q[i].y = fmaf(dQb[i], kRQ[1].y, w1Q[i].y);
      }
      float tp[8];
#pragma unroll
      for (int i = 0; i < 8; ++i) tp[i] = dot2(w1P[i], kRP[4]);
      float tAP = allred4(tp[0], tp[1], tp[2], tp[3]);
      float tBP = allred4(tp[4], tp[5], tp[6], tp[7]);
#pragma unroll
      for (int i = 0; i < 8; ++i) tp[i] = dot2(w1P[i], kRP[5]);
      float uAP = allred4(tp[0], tp[1], tp[2], tp[3]);
      float uBP = allred4(tp[4], tp[5], tp[6], tp[7]);
#pragma unroll
      for (int i = 0; i < 8; ++i) tp[i] = dot2(w1Q[i], kRQ[4]);
      float tAQ = allred4(tp[0], tp[1], tp[2], tp[3]);
      float tBQ = allred4(tp[4], tp[5], tp[6], tp[7]);
#pragma unroll
      for (int i = 0; i < 8; ++i) tp[i] = dot2(w1Q[i], kRQ[5]);
      float uAQ = allred4(tp[0], tp[1], tp[2], tp[3]);
      float uBQ = allred4(tp[4], tp[5], tp[6], tp[7]);
      if (rowlead) {
        sm[tpo + sig] = tAP;           sm[tpo + 4 + sig] = tBP;
        sm[tpo + 8 + sig] = uAP;       sm[tpo + 12 + sig] = uBP;
        sm[80 + tpo + sig] = tAQ;      sm[80 + tpo + 4 + sig] = tBQ;
        sm[80 + tpo + 8 + sig] = uAQ;  sm[80 + tpo + 12 + sig] = uBQ;
      }
      kRP[0] = kRP[2]; kRP[1] = kRP[3]; kRP[2] = kRP[4]; kRP[3] = kRP[5];
      kRP[4] = kIP0;   kRP[5] = kIP1;   kIP0 = nP0;      kIP1 = nP1;
      kRQ[0] = kRQ[2]; kRQ[1] = kRQ[3]; kRQ[2] = kRQ[4]; kRQ[3] = kRQ[5];
      kRQ[4] = kIQ0;   kRQ[5] = kIQ1;   kIQ0 = nQ0;      kIQ1 = nQ1;
      BAR();
    };

    for (int pr = 0; pr < 511; ++pr) {
      EPB(0, 2 * pr);
      EPB(1, 2 * pr + 1);
    }
    EPB(0, 1022);
  }
}

extern "C" void kernel_launch(void* const* d_in, const int* in_sizes, int n_in,
                              void* d_out, int out_size, void* d_ws, size_t ws_size,
                              hipStream_t stream) {
  const float* h  = (const float*)d_in[0];
  const float* W1 = (const float*)d_in[1];
  const float* b1 = (const float*)d_in[2];
  const float* W2 = (const float*)d_in[3];
  const float* b2 = (const float*)d_in[4];
  float* out = (float*)d_out;
  ttt_kernel<<<128, 128, 0, stream>>>(h, W1, b1, W2, b2, out);
}